// Round 5
// baseline (527.041 us; speedup 1.0000x reference)
//
#include <hip/hip_runtime.h>
#include <hip/hip_bf16.h>
#include <stdint.h>

// Problem constants
#define B_ROWS 32768
#define NUM_IN 1024
#define D_PAD2 1088   // 1064 padded to 17*64 K-tiles (8 dbuf iterations + 1 tail tile)
#define HID    2048
#define NPAD   64     // 37 logits padded to 64

typedef __attribute__((ext_vector_type(8))) short bf16x8;
typedef __attribute__((ext_vector_type(4))) float f32x4;
typedef unsigned short ushort_t;

__device__ __forceinline__ unsigned short f2bf(float f){
  union { float f; uint32_t u; } x; x.f = f;
  uint32_t u = x.u;
  return (unsigned short)((u + 0x7FFFu + ((u >> 16) & 1u)) >> 16);
}

__device__ __forceinline__ void gload16(const void* g, void* l){
  __builtin_amdgcn_global_load_lds((const __attribute__((address_space(1))) void*)g,
                                   (__attribute__((address_space(3))) void*)l, 16, 0, 0);
}

// ---------------- discretizer scan (per batch element) ----------------
__device__ __forceinline__ int disc_step(
    float cam0, float cam1, const int a[5],
    float& ac0, float& ac1, float& delta,
    int r[5], bool& dch, int& cam_steps, bool& committed, float& norm)
{
  const int RS[5] = {6, 8, 10, 11, 14};
  norm += committed ? 0.0f : 1.0f;
  bool commit = ((fabsf(cam0) < 1e-5f) && (fabsf(cam1) < 1e-5f)) || (cam_steps >= 6);
  #pragma unroll
  for (int i = 0; i < 5; ++i) commit = commit && (r[i] == a[i]);
  int dac = 0;
  bool modified = commit;
  #pragma unroll
  for (int i = 0; i < 5; ++i){
    bool disc = (!modified) && (r[i] != a[i]);
    if (disc){
      dac = (a[i] == 0) ? (r[i] - 1 + RS[i]) : (a[i] - 1 + RS[i]);
      r[i] = a[i];
      modified = true;
    }
  }
  float d2 = delta * 2.0f;
  // NOTE: reference compares BOTH cam0 and cam1 against ac[:,0] — replicate.
  bool dmask = (!modified) && (!dch) &&
               ((fabsf(cam0 - ac0) > d2) || (fabsf(cam1 - ac0) > d2));
  if (dmask){ dac = 5; delta = fminf(d2, 0.5f); modified = true; }
  if (!modified){
    float sx = (cam0 < ac0) ? -1.0f : 1.0f;
    float sy = (cam1 < ac1) ? -1.0f : 1.0f;
    dac = (sx < 0.0f) ? ((sy < 0.0f) ? 1 : 3) : ((sy < 0.0f) ? 2 : 4);
    ac0 += sx * delta; ac1 += sy * delta;
    delta *= 0.5f;
    dch = true;
    cam_steps += 1;
  }
  committed = committed || commit;
  return dac;
}

// ---------------- fused prep: fc convert | W1^T | W2^T | discretizer ----------------
// block ranges: [0,16384) fc ; [16384,25088) w1t ; [25088,25600) w2t ; [25600,25728) disc
__global__ void k_prep(const float* __restrict__ fc, const float* __restrict__ W1,
                       const float* __restrict__ W2,
                       const float* __restrict__ camera, const float* __restrict__ rand_u,
                       const int* __restrict__ afb, const int* __restrict__ alr,
                       const int* __restrict__ ajp, const int* __restrict__ ass,
                       const int* __restrict__ aat,
                       unsigned short* __restrict__ xb, unsigned short* __restrict__ w1t,
                       unsigned short* __restrict__ w2t, int* __restrict__ tgt)
{
  const int b = blockIdx.x;
  const int tid = threadIdx.x;
  if (b < 16384){
    // fc f32 -> bf16, rows of 1024 into stride-1088 xb
    int gid = b * 256 + tid;
    int row = gid >> 7;
    int c   = gid & 127;
    const float4* p = (const float4*)(fc + (size_t)row * NUM_IN + c * 8);
    float4 f0 = p[0], f1 = p[1];
    uint4 pk;
    pk.x = (uint32_t)f2bf(f0.x) | ((uint32_t)f2bf(f0.y) << 16);
    pk.y = (uint32_t)f2bf(f0.z) | ((uint32_t)f2bf(f0.w) << 16);
    pk.z = (uint32_t)f2bf(f1.x) | ((uint32_t)f2bf(f1.y) << 16);
    pk.w = (uint32_t)f2bf(f1.z) | ((uint32_t)f2bf(f1.w) << 16);
    *(uint4*)(xb + (size_t)row * D_PAD2 + c * 8) = pk;
    return;
  }
  if (b < 25088){
    int idx = (b - 16384) * 256 + tid;        // over 2048*1088
    int n = idx / D_PAD2;
    int k = idx - n * D_PAD2;
    float v = (k < 1064) ? W1[(size_t)k * HID + n] : 0.0f;
    w1t[idx] = f2bf(v);
    return;
  }
  if (b < 25600){
    int idx = (b - 25088) * 256 + tid;        // over 64*2048
    int n = idx >> 11;
    int k = idx & (HID - 1);
    float v = (n < 37) ? W2[(size_t)k * 37 + n] : 0.0f;
    w2t[idx] = f2bf(v);
    return;
  }
  // discretizer
  int row = (b - 25600) * 256 + tid;
  float cam0 = camera[2*row], cam1 = camera[2*row + 1];
  int a[5] = { afb[row], alr[row], ajp[row], ass[row], aat[row] };

  float ac0 = 0.f, ac1 = 0.f, delta = 0.0625f, norm = 0.f;
  int r[5] = {0,0,0,0,0};
  bool dch = false, committed = false; int cam_steps = 0;
  for (int t = 0; t < 20; ++t)
    disc_step(cam0, cam1, a, ac0, ac1, delta, r, dch, cam_steps, committed, norm);

  int rs = (int)(rand_u[row] * norm);
  if (rs > 19) rs = 19;
  if (rs < 0) rs = 0;

  ac0 = 0.f; ac1 = 0.f; delta = 0.0625f; norm = 0.f;
  r[0]=r[1]=r[2]=r[3]=r[4]=0; dch = false; committed = false; cam_steps = 0;
  for (int t = 0; t < rs; ++t)
    disc_step(cam0, cam1, a, ac0, ac1, delta, r, dch, cam_steps, committed, norm);

  float vec[40];
  #pragma unroll
  for (int j = 0; j < 40; ++j) vec[j] = 0.0f;
  vec[0] = ac0; vec[1] = ac1;
  const int offs[5] = {2, 5, 8, 10, 14};
  #pragma unroll
  for (int i = 0; i < 5; ++i) vec[offs[i] + r[i]] = 1.0f;
  vec[38] = delta; vec[39] = dch ? 1.0f : 0.0f;

  int dac = disc_step(cam0, cam1, a, ac0, ac1, delta, r, dch, cam_steps, committed, norm);
  tgt[row] = dac;

  unsigned short* o = xb + (size_t)row * D_PAD2 + NUM_IN;
  #pragma unroll
  for (int j = 0; j < 40; ++j) o[j] = f2bf(vec[j]);
  #pragma unroll
  for (int j = 40; j < 64; ++j) o[j] = 0;   // pad cols 1064..1087
}

// ---------------- GEMM1: 256x256 8-phase, pipelined frags + fused W2 projection ----------------
#define LDS_A0 0
#define LDS_A1 16384
#define LDS_B0 32768
#define LDS_B1 49152

#define STAGE(G, REG, ROW0, KT, HALF) do { \
    const ushort_t* s0_ = (G) + (size_t)((ROW0) + (HALF)*128 + srow) * D_PAD2 + ((KT) << 6) + scol; \
    gload16(s0_, lds + (REG) + (HALF)*8192 + t*8); \
    gload16(s0_ + (size_t)64 * D_PAD2, lds + (REG) + (HALF)*8192 + 4096 + t*8); \
  } while(0)

// read an A fragment batch (8 x ds_read_b128) into bank BANK
#define RDA(BANK, REG, MH) do { \
    _Pragma("unroll") for (int mi_ = 0; mi_ < 4; ++mi_){ \
      const int row_ = arow_base + (MH)*64 + mi_*16; \
      _Pragma("unroll") for (int kk_ = 0; kk_ < 2; ++kk_) \
        BANK[mi_][kk_] = *(const bf16x8*)(lds + (REG) + row_*64 + (((kk_*4+lg)^axor)<<3)); \
    } \
  } while(0)

// read BOTH B half-fragments of one K-tile (8 x ds_read_b128) into bank BANK
#define RDB(BANK, REG) do { \
    _Pragma("unroll") for (int nh_ = 0; nh_ < 2; ++nh_) \
    _Pragma("unroll") for (int ni_ = 0; ni_ < 2; ++ni_){ \
      const int row_ = brow_base + nh_*32 + ni_*16; \
      _Pragma("unroll") for (int kk_ = 0; kk_ < 2; ++kk_) \
        BANK[nh_][ni_][kk_] = *(const bf16x8*)(lds + (REG) + row_*64 + (((kk_*4+lg)^axor)<<3)); \
    } \
  } while(0)

// one C-quadrant: 16 MFMAs. Compiler auto-inserts counted lgkmcnt before first use.
#define MMAQ(AB, MH, BB, NH) do { \
    __builtin_amdgcn_s_setprio(1); \
    _Pragma("unroll") for (int mi_ = 0; mi_ < 4; ++mi_) \
    _Pragma("unroll") for (int ni_ = 0; ni_ < 2; ++ni_) \
    _Pragma("unroll") for (int kk_ = 0; kk_ < 2; ++kk_) \
      acc[(MH)*4+mi_][(NH)*2+ni_] = __builtin_amdgcn_mfma_f32_16x16x32_bf16( \
          AB[mi_][kk_], BB[NH][ni_][kk_], acc[(MH)*4+mi_][(NH)*2+ni_], 0, 0, 0); \
    __builtin_amdgcn_s_setprio(0); \
  } while(0)

#define BAR() __builtin_amdgcn_s_barrier()
#define WAIT_VM6()   asm volatile("s_waitcnt vmcnt(6)" ::: "memory")
#define WAIT_VM0()   asm volatile("s_waitcnt vmcnt(0)" ::: "memory")

__global__ __launch_bounds__(512, 2) void k_gemm1(const ushort_t* __restrict__ xb,
                                                  const ushort_t* __restrict__ w1t,
                                                  const ushort_t* __restrict__ w2t,
                                                  const float* __restrict__ b1,
                                                  float* __restrict__ pbuf)
{
  __shared__ ushort_t lds[65536];   // 128 KiB
  const int t = threadIdx.x;        // 0..511
  const int lane = t & 63;
  const int wid = t >> 6, wm = wid >> 2, wn = wid & 3;
  const int lr = lane & 15, lg = lane >> 4;

  // XCD-aware swizzle (nwg=1024 divisible by 8 -> bijective).
  const int bid = blockIdx.x;
  const int swz = (bid & 7) * 128 + (bid >> 3);
  const int brow = (swz >> 3) << 8;   // 128 row tiles of 256
  const int bcol = (swz & 7) << 8;    // 8 col tiles of 256

  // staging coords
  const int srow = t >> 3;                          // 0..63
  const int scol = ((t & 7) ^ (srow & 7)) << 3;     // pre-swizzled source chunk

  // fragment coords
  const int axor = lr & 7;
  const int arow_base = wm*128 + lr;
  const int brow_base = wn*64 + lr;

  f32x4 acc[8][4] = {};
  // double-banked fragment registers: aA=mh0, aB=mh1; bX=even K-tile B, bY=odd
  bf16x8 aA[4][2], aB[4][2], bX[2][2][2], bY[2][2][2];

  // ---- prologue: tile0 -> buf0 (4 halves), tile1 -> buf1 (B h0,h1 + A h0)
  STAGE(xb,  LDS_A0, brow, 0, 0);  STAGE(xb,  LDS_A0, brow, 0, 1);
  STAGE(w1t, LDS_B0, bcol, 0, 0);  STAGE(w1t, LDS_B0, bcol, 0, 1);
  STAGE(w1t, LDS_B1, bcol, 1, 0);  STAGE(w1t, LDS_B1, bcol, 1, 1);
  STAGE(xb,  LDS_A1, brow, 1, 0);
  WAIT_VM6();            // 14 loads issued, <=6 outstanding -> tile0 landed
  BAR();
  // initial fragment prefetch for iteration 0 (tile 0)
  RDA(aA, LDS_A0, 0); RDB(bX, LDS_B0);

  // 8 double-buffered iterations over tiles 0..15; tile 16 handled in tail.
  for (int i = 0; i < 8; ++i){
    const int c1 = 2*i + 1;
    const int n0 = 2*i + 2;                          // <= 16, real tile
    const int n1 = (2*i + 3 <= 16) ? 2*i + 3 : 16;   // i=7: redundant re-stage, benign

    // S0: stage A1.h1 (tile c1)
    STAGE(xb, LDS_A1, brow, c1, 1);
    BAR();
    // S1: prefetch A0mh1 || MFMA Q(0,0) on (aA,bX)
    RDA(aB, LDS_A0, 1);
    MMAQ(aA, 0, bX, 0);
    BAR();
    // S2: stage B0.h0 (tile n0; B0 reads completed at S1's wait + barrier)
    STAGE(w1t, LDS_B0, bcol, n0, 0);
    BAR();
    // S3: MFMA Q(0,1)
    MMAQ(aA, 0, bX, 1);
    BAR();
    // S4: stage B0.h1
    STAGE(w1t, LDS_B0, bcol, n0, 1);
    BAR();
    // S5: MFMA Q(1,0)  (aB drained by compiler wait)
    MMAQ(aB, 1, bX, 0);
    BAR();
    // S6: stage A0.h0; counted vmcnt -> tile c1 (A1.h1) + prev B1/A1 landed
    STAGE(xb, LDS_A0, brow, n0, 0);
    WAIT_VM6();
    BAR();
    // S7: prefetch A1mh0 + all B1 (tile c1) || MFMA Q(1,1)
    RDA(aA, LDS_A1, 0); RDB(bY, LDS_B1);
    MMAQ(aB, 1, bX, 1);
    BAR();
    // S8: stage A0.h1
    STAGE(xb, LDS_A0, brow, n0, 1);
    BAR();
    // S9: prefetch A1mh1 || MFMA Q(0,0) on (aA,bY)
    RDA(aB, LDS_A1, 1);
    MMAQ(aA, 0, bY, 0);
    BAR();
    // S10: stage B1.h0 (tile n1; bY reads of B1 completed at S9's wait + barrier)
    STAGE(w1t, LDS_B1, bcol, n1, 0);
    BAR();
    // S11: MFMA Q(0,1)
    MMAQ(aA, 0, bY, 1);
    BAR();
    // S12: stage B1.h1
    STAGE(w1t, LDS_B1, bcol, n1, 1);
    BAR();
    // S13: MFMA Q(1,0)
    MMAQ(aB, 1, bY, 0);
    BAR();
    // S14: stage A1.h0; counted vmcnt -> tile n0 (A0/B0) landed
    STAGE(xb, LDS_A1, brow, n1, 0);
    WAIT_VM6();
    BAR();
    // S15: prefetch next iteration's A0mh0 + B0 (tile n0) || MFMA Q(1,1)
    RDA(aA, LDS_A0, 0); RDB(bX, LDS_B0);
    MMAQ(aB, 1, bY, 1);
    BAR();
  }

  // ---- tail: tile 16 in A0/B0; aA/bX pre-read in last S15 (data landed per S14 vm6)
  MMAQ(aA, 0, bX, 0);
  RDA(aB, LDS_A0, 1);
  MMAQ(aA, 0, bX, 1);
  MMAQ(aB, 1, bX, 0);
  MMAQ(aB, 1, bX, 1);

  // ---- fused epilogue ----
  // Batch 1 of W2 fragments (ks 0..3): issue now, latency hides under silu/ds_writes.
  bf16x8 w2fA[4][4];
  #pragma unroll
  for (int ks = 0; ks < 4; ++ks)
    #pragma unroll
    for (int ni = 0; ni < 4; ++ni)
      w2fA[ks][ni] = *(const bf16x8*)(w2t + (size_t)(ni*16 + lr) * HID + bcol + ks*32 + lg*8);

  // Drain pending (clamped) prefetches before reusing LDS, then sync.
  WAIT_VM0();
  BAR();

  float b1v[4];
  #pragma unroll
  for (int ni = 0; ni < 4; ++ni) b1v[ni] = b1[bcol + wn*64 + ni*16 + lr];

  // silu + pack to bf16; scatter into LDS as [row 256][col 256] with chunk-XOR swizzle
  #pragma unroll
  for (int mi = 0; mi < 8; ++mi){
    #pragma unroll
    for (int ni = 0; ni < 4; ++ni){
      const int col = wn*64 + ni*16 + lr;
      #pragma unroll
      for (int i2 = 0; i2 < 4; ++i2){
        const int row = wm*128 + mi*16 + lg*4 + i2;
        float v = acc[mi][ni][i2] + b1v[ni];
        float s = v / (1.0f + __expf(-v));     // silu
        const int chunk = (col >> 3) ^ (row & 7);
        lds[row*256 + chunk*8 + (col & 7)] = f2bf(s);
      }
    }
  }
  __syncthreads();

  // Batch 2 of W2 fragments (ks 4..7): latency hides under first 4 ks of MFMA.
  bf16x8 w2fB[4][4];
  #pragma unroll
  for (int ks = 0; ks < 4; ++ks)
    #pragma unroll
    for (int ni = 0; ni < 4; ++ni)
      w2fB[ks][ni] = *(const bf16x8*)(w2t + (size_t)(ni*16 + lr) * HID + bcol + (ks+4)*32 + lg*8);

  // mini-GEMM: partial[r][n] = hTile[r][:256] @ W2chunk[:256][n], n in [0,64)
  const int rb = wid * 32;
  f32x4 acc2[2][4] = {};
  #pragma unroll
  for (int ks = 0; ks < 8; ++ks){
    bf16x8 a2[2];
    #pragma unroll
    for (int m = 0; m < 2; ++m){
      const int row = rb + m*16 + lr;
      a2[m] = *(const bf16x8*)(lds + row*256 + (((ks*4+lg) ^ (lr & 7)) << 3));
    }
    #pragma unroll
    for (int m = 0; m < 2; ++m)
      #pragma unroll
      for (int ni = 0; ni < 4; ++ni)
        acc2[m][ni] = __builtin_amdgcn_mfma_f32_16x16x32_bf16(
            a2[m], (ks < 4) ? w2fA[ks & 3][ni] : w2fB[ks & 3][ni], acc2[m][ni], 0, 0, 0);
  }

  // store partials: pbuf[cb][row][col]
  const int cb = bcol >> 8;
  #pragma unroll
  for (int m = 0; m < 2; ++m)
    #pragma unroll
    for (int ni = 0; ni < 4; ++ni)
      #pragma unroll
      for (int i2 = 0; i2 < 4; ++i2){
        const int r = brow + rb + m*16 + lg*4 + i2;
        pbuf[((size_t)cb << 21) + ((size_t)r << 6) + ni*16 + lr] = acc2[m][ni][i2];
      }
}

// ---------------- reduce: sum partials + b2 -> log-softmax -> NLL ----------------
__global__ __launch_bounds__(256) void k_red(const float* __restrict__ pbuf,
                                             const float* __restrict__ b2,
                                             const int* __restrict__ tgt,
                                             float* __restrict__ loss)
{
  const int lane = threadIdx.x & 63, w = threadIdx.x >> 6;
  const int row0 = blockIdx.x * 128 + w * 32;
  const float bias = (lane < 37) ? b2[lane] : 0.0f;
  for (int i = 0; i < 32; ++i){
    const int r = row0 + i;
    float s = 0.0f;
    #pragma unroll
    for (int cb = 0; cb < 8; ++cb)
      s += pbuf[((size_t)cb << 21) + ((size_t)r << 6) + lane];
    float x = (lane < 37) ? (s + bias) : -1e30f;
    float m = x;
    #pragma unroll
    for (int off = 1; off < 64; off <<= 1) m = fmaxf(m, __shfl_xor(m, off, 64));
    float e = __expf(x - m);
    float se = e;
    #pragma unroll
    for (int off = 1; off < 64; off <<= 1) se += __shfl_xor(se, off, 64);
    const int tg = tgt[r];
    const float pick = __shfl(x, tg, 64);
    if (lane == 0) loss[r] = m + __logf(se) - pick;
  }
}

// ---------------- launch ----------------
extern "C" void kernel_launch(void* const* d_in, const int* in_sizes, int n_in,
                              void* d_out, int out_size, void* d_ws, size_t ws_size,
                              hipStream_t stream)
{
  (void)in_sizes; (void)n_in; (void)out_size; (void)ws_size;
  const float* fc  = (const float*)d_in[0];
  const float* cam = (const float*)d_in[1];
  const float* ru  = (const float*)d_in[2];
  const float* W1  = (const float*)d_in[3];
  const float* b1  = (const float*)d_in[4];
  const float* W2  = (const float*)d_in[5];
  const float* b2  = (const float*)d_in[6];
  const int* afb = (const int*)d_in[7];
  const int* alr = (const int*)d_in[8];
  const int* ajp = (const int*)d_in[9];
  const int* ass = (const int*)d_in[10];
  const int* aat = (const int*)d_in[11];
  float* loss = (float*)d_out;

  // workspace layout (bytes):
  // xb   : 32768 x 1088 bf16  = 71,303,168
  // w1t  : 2048 x 1088 bf16   =  4,456,448
  // w2t  : 64 x 2048 bf16     =    262,144
  // tgt  : 32768 int32        =    131,072
  // pbuf : 8 x 32768 x 64 f32 = 67,108,864   (total ~136.6 MiB)
  char* ws = (char*)d_ws;
  unsigned short* xb  = (unsigned short*)(ws);
  unsigned short* w1t = (unsigned short*)(ws + 71303168);
  unsigned short* w2t = (unsigned short*)(ws + 75759616);
  int*            tgt = (int*)           (ws + 76021760);
  float*          pbuf= (float*)         (ws + 76152832);

  // fused prep: fc(16384) + w1t(8704) + w2t(512) + disc(128) = 25728 blocks
  k_prep<<<25728, 256, 0, stream>>>(fc, W1, W2, cam, ru, afb, alr, ajp, ass, aat,
                                    xb, w1t, w2t, tgt);
  k_gemm1<<<(B_ROWS/256) * (HID/256), 512, 0, stream>>>(xb, w1t, w2t, b1, pbuf);
  k_red  <<<B_ROWS / 128, 256, 0, stream>>>(pbuf, b2, tgt, loss);
}

// Round 6
// 269.634 us; speedup vs baseline: 1.9547x; 1.9547x over previous
//
#include <hip/hip_runtime.h>
#include <hip/hip_bf16.h>
#include <stdint.h>

// Problem constants
#define B_ROWS 32768
#define NUM_IN 1024
#define D_PAD2 1088   // 1064 padded to 17*64 K-tiles (8 dbuf iterations + 1 tail tile)
#define HID    2048
#define NPAD   64     // 37 logits padded to 64

typedef __attribute__((ext_vector_type(8))) short bf16x8;
typedef __attribute__((ext_vector_type(4))) float f32x4;
typedef unsigned short ushort_t;

__device__ __forceinline__ unsigned short f2bf(float f){
  union { float f; uint32_t u; } x; x.f = f;
  uint32_t u = x.u;
  return (unsigned short)((u + 0x7FFFu + ((u >> 16) & 1u)) >> 16);
}

__device__ __forceinline__ void gload16(const void* g, void* l){
  __builtin_amdgcn_global_load_lds((const __attribute__((address_space(1))) void*)g,
                                   (__attribute__((address_space(3))) void*)l, 16, 0, 0);
}

// ---------------- discretizer scan (per batch element) ----------------
__device__ __forceinline__ int disc_step(
    float cam0, float cam1, const int a[5],
    float& ac0, float& ac1, float& delta,
    int r[5], bool& dch, int& cam_steps, bool& committed, float& norm)
{
  const int RS[5] = {6, 8, 10, 11, 14};
  norm += committed ? 0.0f : 1.0f;
  bool commit = ((fabsf(cam0) < 1e-5f) && (fabsf(cam1) < 1e-5f)) || (cam_steps >= 6);
  #pragma unroll
  for (int i = 0; i < 5; ++i) commit = commit && (r[i] == a[i]);
  int dac = 0;
  bool modified = commit;
  #pragma unroll
  for (int i = 0; i < 5; ++i){
    bool disc = (!modified) && (r[i] != a[i]);
    if (disc){
      dac = (a[i] == 0) ? (r[i] - 1 + RS[i]) : (a[i] - 1 + RS[i]);
      r[i] = a[i];
      modified = true;
    }
  }
  float d2 = delta * 2.0f;
  // NOTE: reference compares BOTH cam0 and cam1 against ac[:,0] — replicate.
  bool dmask = (!modified) && (!dch) &&
               ((fabsf(cam0 - ac0) > d2) || (fabsf(cam1 - ac0) > d2));
  if (dmask){ dac = 5; delta = fminf(d2, 0.5f); modified = true; }
  if (!modified){
    float sx = (cam0 < ac0) ? -1.0f : 1.0f;
    float sy = (cam1 < ac1) ? -1.0f : 1.0f;
    dac = (sx < 0.0f) ? ((sy < 0.0f) ? 1 : 3) : ((sy < 0.0f) ? 2 : 4);
    ac0 += sx * delta; ac1 += sy * delta;
    delta *= 0.5f;
    dch = true;
    cam_steps += 1;
  }
  committed = committed || commit;
  return dac;
}

// ---------------- fused prep: fc convert | W1^T (LDS transpose) | W2^T | disc ----------------
// block ranges: [0,16384) fc ; [16384,16928) w1t-transpose (17x32 tiles of 64x64);
//               [16928,17440) w2t ; [17440,17568) disc
__global__ void k_prep(const float* __restrict__ fc, const float* __restrict__ W1,
                       const float* __restrict__ W2,
                       const float* __restrict__ camera, const float* __restrict__ rand_u,
                       const int* __restrict__ afb, const int* __restrict__ alr,
                       const int* __restrict__ ajp, const int* __restrict__ ass,
                       const int* __restrict__ aat,
                       unsigned short* __restrict__ xb, unsigned short* __restrict__ w1t,
                       unsigned short* __restrict__ w2t, int* __restrict__ tgt)
{
  __shared__ float lt[64][65];      // transpose tile (+1 pad, conflict-free)
  const int b = blockIdx.x;
  const int tid = threadIdx.x;
  if (b < 16384){
    // fc f32 -> bf16, rows of 1024 into stride-1088 xb (both sides coalesced)
    int gid = b * 256 + tid;
    int row = gid >> 7;
    int c   = gid & 127;
    const float4* p = (const float4*)(fc + (size_t)row * NUM_IN + c * 8);
    float4 f0 = p[0], f1 = p[1];
    uint4 pk;
    pk.x = (uint32_t)f2bf(f0.x) | ((uint32_t)f2bf(f0.y) << 16);
    pk.y = (uint32_t)f2bf(f0.z) | ((uint32_t)f2bf(f0.w) << 16);
    pk.z = (uint32_t)f2bf(f1.x) | ((uint32_t)f2bf(f1.y) << 16);
    pk.w = (uint32_t)f2bf(f1.z) | ((uint32_t)f2bf(f1.w) << 16);
    *(uint4*)(xb + (size_t)row * D_PAD2 + c * 8) = pk;
    return;
  }
  if (b < 16928){
    // W1 [1064][2048] -> w1t [2048][1088] via 64x64 LDS tile; coalesced both sides
    const int bi = b - 16384;
    const int kt = bi % 17, nt = bi / 17;
    const int k0 = kt * 64, n0 = nt * 64;
    const int c = tid & 63, rq = tid >> 6;       // c: fast lane dim; rq: 0..3
    #pragma unroll
    for (int rr = 0; rr < 16; ++rr){
      const int r = rr * 4 + rq;
      const int k = k0 + r;
      lt[r][c] = (k < 1064) ? W1[(size_t)k * HID + n0 + c] : 0.0f;
    }
    __syncthreads();
    #pragma unroll
    for (int rr = 0; rr < 16; ++rr){
      const int r = rr * 4 + rq;                 // output row n = n0 + r
      w1t[(size_t)(n0 + r) * D_PAD2 + k0 + c] = f2bf(lt[c][r]);
    }
    return;
  }
  if (b < 17440){
    int idx = (b - 16928) * 256 + tid;           // over 64*2048 (W2 tiny, L2-absorbed)
    int n = idx >> 11;
    int k = idx & (HID - 1);
    float v = (n < 37) ? W2[(size_t)k * 37 + n] : 0.0f;
    w2t[idx] = f2bf(v);
    return;
  }
  // discretizer
  int row = (b - 17440) * 256 + tid;
  float cam0 = camera[2*row], cam1 = camera[2*row + 1];
  int a[5] = { afb[row], alr[row], ajp[row], ass[row], aat[row] };

  float ac0 = 0.f, ac1 = 0.f, delta = 0.0625f, norm = 0.f;
  int r[5] = {0,0,0,0,0};
  bool dch = false, committed = false; int cam_steps = 0;
  for (int t = 0; t < 20; ++t)
    disc_step(cam0, cam1, a, ac0, ac1, delta, r, dch, cam_steps, committed, norm);

  int rs = (int)(rand_u[row] * norm);
  if (rs > 19) rs = 19;
  if (rs < 0) rs = 0;

  ac0 = 0.f; ac1 = 0.f; delta = 0.0625f; norm = 0.f;
  r[0]=r[1]=r[2]=r[3]=r[4]=0; dch = false; committed = false; cam_steps = 0;
  for (int t = 0; t < rs; ++t)
    disc_step(cam0, cam1, a, ac0, ac1, delta, r, dch, cam_steps, committed, norm);

  float vec[40];
  #pragma unroll
  for (int j = 0; j < 40; ++j) vec[j] = 0.0f;
  vec[0] = ac0; vec[1] = ac1;
  const int offs[5] = {2, 5, 8, 10, 14};
  #pragma unroll
  for (int i = 0; i < 5; ++i) vec[offs[i] + r[i]] = 1.0f;
  vec[38] = delta; vec[39] = dch ? 1.0f : 0.0f;

  int dac = disc_step(cam0, cam1, a, ac0, ac1, delta, r, dch, cam_steps, committed, norm);
  tgt[row] = dac;

  unsigned short* o = xb + (size_t)row * D_PAD2 + NUM_IN;
  #pragma unroll
  for (int j = 0; j < 40; ++j) o[j] = f2bf(vec[j]);
  #pragma unroll
  for (int j = 40; j < 64; ++j) o[j] = 0;   // pad cols 1064..1087
}

// ---------------- GEMM1: 256x256 true 8-phase (MFMA in EVERY phase) + fused W2 ----------------
#define LDS_A0 0
#define LDS_A1 16384
#define LDS_B0 32768
#define LDS_B1 49152

#define STAGE(G, REG, ROW0, KT, HALF) do { \
    const ushort_t* s0_ = (G) + (size_t)((ROW0) + (HALF)*128 + srow) * D_PAD2 + ((KT) << 6) + scol; \
    gload16(s0_, lds + (REG) + (HALF)*8192 + t*8); \
    gload16(s0_ + (size_t)64 * D_PAD2, lds + (REG) + (HALF)*8192 + 4096 + t*8); \
  } while(0)

// A fragment batch (8 x ds_read_b128) into the single aR bank
#define LDA_(REG, MH) do { \
    _Pragma("unroll") for (int mi_ = 0; mi_ < 4; ++mi_){ \
      const int row_ = arow_base + (MH)*64 + mi_*16; \
      _Pragma("unroll") for (int kk_ = 0; kk_ < 2; ++kk_) \
        aR[mi_][kk_] = *(const bf16x8*)(lds + (REG) + row_*64 + (((kk_*4+lg)^axor)<<3)); \
    } \
  } while(0)

// B half-quadrant (4 x ds_read_b128) into bank BR
#define LDB_(REG, NH, BR) do { \
    _Pragma("unroll") for (int ni_ = 0; ni_ < 2; ++ni_){ \
      const int row_ = brow_base + (NH)*32 + ni_*16; \
      _Pragma("unroll") for (int kk_ = 0; kk_ < 2; ++kk_) \
        BR[ni_][kk_] = *(const bf16x8*)(lds + (REG) + row_*64 + (((kk_*4+lg)^axor)<<3)); \
    } \
  } while(0)

#define MMA(MH, NH, BR) do { \
    __builtin_amdgcn_s_setprio(1); \
    _Pragma("unroll") for (int mi_ = 0; mi_ < 4; ++mi_) \
    _Pragma("unroll") for (int ni_ = 0; ni_ < 2; ++ni_) \
    _Pragma("unroll") for (int kk_ = 0; kk_ < 2; ++kk_) \
      acc[(MH)*4+mi_][(NH)*2+ni_] = __builtin_amdgcn_mfma_f32_16x16x32_bf16( \
          aR[mi_][kk_], BR[ni_][kk_], acc[(MH)*4+mi_][(NH)*2+ni_], 0, 0, 0); \
    __builtin_amdgcn_s_setprio(0); \
  } while(0)

#define BAR() __builtin_amdgcn_s_barrier()
#define LGKM0()      asm volatile("s_waitcnt lgkmcnt(0)" ::: "memory")
#define WAIT_VM6()   asm volatile("s_waitcnt vmcnt(6)" ::: "memory")
#define WAIT_VM0()   asm volatile("s_waitcnt vmcnt(0)" ::: "memory")

__global__ __launch_bounds__(512, 2) void k_gemm1(const ushort_t* __restrict__ xb,
                                                  const ushort_t* __restrict__ w1t,
                                                  const ushort_t* __restrict__ w2t,
                                                  const float* __restrict__ b1,
                                                  float* __restrict__ pbuf)
{
  __shared__ ushort_t lds[65536];   // 128 KiB
  const int t = threadIdx.x;        // 0..511
  const int lane = t & 63;
  const int wid = t >> 6, wm = wid >> 2, wn = wid & 3;
  const int lr = lane & 15, lg = lane >> 4;

  // XCD-aware swizzle (nwg=1024 divisible by 8 -> bijective).
  const int bid = blockIdx.x;
  const int swz = (bid & 7) * 128 + (bid >> 3);
  const int brow = (swz >> 3) << 8;   // 128 row tiles of 256
  const int bcol = (swz & 7) << 8;    // 8 col tiles of 256

  // staging coords
  const int srow = t >> 3;                          // 0..63
  const int scol = ((t & 7) ^ (srow & 7)) << 3;     // pre-swizzled source chunk

  // fragment coords
  const int axor = lr & 7;
  const int arow_base = wm*128 + lr;
  const int brow_base = wn*64 + lr;

  f32x4 acc[8][4] = {};
  bf16x8 aR[4][2], bR0[2][2], bR1[2][2];   // same register set as round 4 (no spill)

  // ---- prologue: tile0 full + tile1 partial (A1h0, B1h0, B1h1); A1h1 staged at P1.
  STAGE(xb,  LDS_A0, brow, 0, 0);  STAGE(xb,  LDS_A0, brow, 0, 1);
  STAGE(w1t, LDS_B0, bcol, 0, 0);  STAGE(w1t, LDS_B0, bcol, 0, 1);
  STAGE(xb,  LDS_A1, brow, 1, 0);
  STAGE(w1t, LDS_B1, bcol, 1, 0);  STAGE(w1t, LDS_B1, bcol, 1, 1);
  WAIT_VM6();            // newest 6 = A1h0,B1h0,B1h1 -> tile0 (A0,B0) landed
  BAR();

  // 8 iterations over tiles 0..15; tile 16 in tail.
  // Phase = { frag ds_reads | 1 STAGE -> BAR -> lgkm0 -> 16 MFMA -> BAR }.
  // Region-freeness: B0 free after P1, A0 after P3, B1 after P5, A1 after P7.
  // Landing: vm6 at P4 (covers A1 tile c1 + B1) and P8 (covers A0/B0 tile n0).
  for (int i = 0; i < 8; ++i){
    const int c1 = 2*i + 1;
    const int n0 = 2*i + 2;                          // <= 16, real tile
    const int n1 = (2*i + 3 <= 16) ? 2*i + 3 : 16;   // i=7: garbage into unused A1/B1, benign

    // P1: reads A0mh0 + ALL B0 ; stage A1h1 (tile c1)
    LDA_(LDS_A0, 0); LDB_(LDS_B0, 0, bR0); LDB_(LDS_B0, 1, bR1);
    STAGE(xb, LDS_A1, brow, c1, 1);
    BAR(); LGKM0();
    MMA(0, 0, bR0);
    BAR();
    // P2: stage B0h0 (tile n0)
    STAGE(w1t, LDS_B0, bcol, n0, 0);
    BAR();
    MMA(0, 1, bR1);
    BAR();
    // P3: reads A0mh1 ; stage B0h1
    LDA_(LDS_A0, 1);
    STAGE(w1t, LDS_B0, bcol, n0, 1);
    BAR(); LGKM0();
    MMA(1, 0, bR0);
    BAR();
    // P4: stage A0h0 ; vm6 -> tile c1 (A1h1 + older) landed
    STAGE(xb, LDS_A0, brow, n0, 0);
    WAIT_VM6();
    BAR();
    MMA(1, 1, bR1);
    BAR();
    // P5: reads A1mh0 + ALL B1 (tile c1) ; stage A0h1
    LDA_(LDS_A1, 0); LDB_(LDS_B1, 0, bR0); LDB_(LDS_B1, 1, bR1);
    STAGE(xb, LDS_A0, brow, n0, 1);
    BAR(); LGKM0();
    MMA(0, 0, bR0);
    BAR();
    // P6: stage B1h0 (tile n1)
    STAGE(w1t, LDS_B1, bcol, n1, 0);
    BAR();
    MMA(0, 1, bR1);
    BAR();
    // P7: reads A1mh1 ; stage B1h1
    LDA_(LDS_A1, 1);
    STAGE(w1t, LDS_B1, bcol, n1, 1);
    BAR(); LGKM0();
    MMA(1, 0, bR0);
    BAR();
    // P8: stage A1h0 ; vm6 -> tile n0 (A0,B0) landed
    STAGE(xb, LDS_A1, brow, n1, 0);
    WAIT_VM6();
    BAR();
    MMA(1, 1, bR1);
    BAR();
  }

  // ---- tail: tile 16 in A0/B0 (landed per last P8's vm6+BAR).
  LDA_(LDS_A0, 0); LDB_(LDS_B0, 0, bR0); LDB_(LDS_B0, 1, bR1);
  LGKM0();
  MMA(0, 0, bR0); MMA(0, 1, bR1);
  LDA_(LDS_A0, 1);
  LGKM0();
  MMA(1, 0, bR0); MMA(1, 1, bR1);

  // ---- fused epilogue ----
  // Batch 1 of W2 fragments (ks 0..3): issue now, latency hides under silu/ds_writes.
  bf16x8 w2fA[4][4];
  #pragma unroll
  for (int ks = 0; ks < 4; ++ks)
    #pragma unroll
    for (int ni = 0; ni < 4; ++ni)
      w2fA[ks][ni] = *(const bf16x8*)(w2t + (size_t)(ni*16 + lr) * HID + bcol + ks*32 + lg*8);

  // Drain pending (garbage) prefetches before reusing LDS, then sync.
  WAIT_VM0();
  BAR();

  float b1v[4];
  #pragma unroll
  for (int ni = 0; ni < 4; ++ni) b1v[ni] = b1[bcol + wn*64 + ni*16 + lr];

  // silu + pack to bf16; scatter into LDS as [row 256][col 256] with chunk-XOR swizzle
  #pragma unroll
  for (int mi = 0; mi < 8; ++mi){
    #pragma unroll
    for (int ni = 0; ni < 4; ++ni){
      const int col = wn*64 + ni*16 + lr;
      #pragma unroll
      for (int i2 = 0; i2 < 4; ++i2){
        const int row = wm*128 + mi*16 + lg*4 + i2;
        float v = acc[mi][ni][i2] + b1v[ni];
        float s = v / (1.0f + __expf(-v));     // silu
        const int chunk = (col >> 3) ^ (row & 7);
        lds[row*256 + chunk*8 + (col & 7)] = f2bf(s);
      }
    }
  }
  __syncthreads();

  // Batch 2 of W2 fragments (ks 4..7): latency hides under first 4 ks of MFMA.
  bf16x8 w2fB[4][4];
  #pragma unroll
  for (int ks = 0; ks < 4; ++ks)
    #pragma unroll
    for (int ni = 0; ni < 4; ++ni)
      w2fB[ks][ni] = *(const bf16x8*)(w2t + (size_t)(ni*16 + lr) * HID + bcol + (ks+4)*32 + lg*8);

  // mini-GEMM: partial[r][n] = hTile[r][:256] @ W2chunk[:256][n], n in [0,64)
  const int rb = wid * 32;
  f32x4 acc2[2][4] = {};
  #pragma unroll
  for (int ks = 0; ks < 8; ++ks){
    bf16x8 a2[2];
    #pragma unroll
    for (int m = 0; m < 2; ++m){
      const int row = rb + m*16 + lr;
      a2[m] = *(const bf16x8*)(lds + row*256 + (((ks*4+lg) ^ (lr & 7)) << 3));
    }
    #pragma unroll
    for (int m = 0; m < 2; ++m)
      #pragma unroll
      for (int ni = 0; ni < 4; ++ni)
        acc2[m][ni] = __builtin_amdgcn_mfma_f32_16x16x32_bf16(
            a2[m], (ks < 4) ? w2fA[ks & 3][ni] : w2fB[ks & 3][ni], acc2[m][ni], 0, 0, 0);
  }

  // store partials: pbuf[cb][row][col]
  const int cb = bcol >> 8;
  #pragma unroll
  for (int m = 0; m < 2; ++m)
    #pragma unroll
    for (int ni = 0; ni < 4; ++ni)
      #pragma unroll
      for (int i2 = 0; i2 < 4; ++i2){
        const int r = brow + rb + m*16 + lg*4 + i2;
        pbuf[((size_t)cb << 21) + ((size_t)r << 6) + ni*16 + lr] = acc2[m][ni][i2];
      }
}

// ---------------- reduce: sum partials + b2 -> log-softmax -> NLL ----------------
__global__ __launch_bounds__(256) void k_red(const float* __restrict__ pbuf,
                                             const float* __restrict__ b2,
                                             const int* __restrict__ tgt,
                                             float* __restrict__ loss)
{
  const int lane = threadIdx.x & 63, w = threadIdx.x >> 6;
  const int row0 = blockIdx.x * 128 + w * 32;
  const float bias = (lane < 37) ? b2[lane] : 0.0f;
  for (int i = 0; i < 32; ++i){
    const int r = row0 + i;
    float s = 0.0f;
    #pragma unroll
    for (int cb = 0; cb < 8; ++cb)
      s += pbuf[((size_t)cb << 21) + ((size_t)r << 6) + lane];
    float x = (lane < 37) ? (s + bias) : -1e30f;
    float m = x;
    #pragma unroll
    for (int off = 1; off < 64; off <<= 1) m = fmaxf(m, __shfl_xor(m, off, 64));
    float e = __expf(x - m);
    float se = e;
    #pragma unroll
    for (int off = 1; off < 64; off <<= 1) se += __shfl_xor(se, off, 64);
    const int tg = tgt[r];
    const float pick = __shfl(x, tg, 64);
    if (lane == 0) loss[r] = m + __logf(se) - pick;
  }
}

// ---------------- launch ----------------
extern "C" void kernel_launch(void* const* d_in, const int* in_sizes, int n_in,
                              void* d_out, int out_size, void* d_ws, size_t ws_size,
                              hipStream_t stream)
{
  (void)in_sizes; (void)n_in; (void)out_size; (void)ws_size;
  const float* fc  = (const float*)d_in[0];
  const float* cam = (const float*)d_in[1];
  const float* ru  = (const float*)d_in[2];
  const float* W1  = (const float*)d_in[3];
  const float* b1  = (const float*)d_in[4];
  const float* W2  = (const float*)d_in[5];
  const float* b2  = (const float*)d_in[6];
  const int* afb = (const int*)d_in[7];
  const int* alr = (const int*)d_in[8];
  const int* ajp = (const int*)d_in[9];
  const int* ass = (const int*)d_in[10];
  const int* aat = (const int*)d_in[11];
  float* loss = (float*)d_out;

  // workspace layout (bytes):
  // xb   : 32768 x 1088 bf16  = 71,303,168
  // w1t  : 2048 x 1088 bf16   =  4,456,448
  // w2t  : 64 x 2048 bf16     =    262,144
  // tgt  : 32768 int32        =    131,072
  // pbuf : 8 x 32768 x 64 f32 = 67,108,864   (total ~136.6 MiB)
  char* ws = (char*)d_ws;
  unsigned short* xb  = (unsigned short*)(ws);
  unsigned short* w1t = (unsigned short*)(ws + 71303168);
  unsigned short* w2t = (unsigned short*)(ws + 75759616);
  int*            tgt = (int*)           (ws + 76021760);
  float*          pbuf= (float*)         (ws + 76152832);

  // fused prep: fc(16384) + w1t-transpose(544) + w2t(512) + disc(128) = 17568 blocks
  k_prep<<<17568, 256, 0, stream>>>(fc, W1, W2, cam, ru, afb, alr, ajp, ass, aat,
                                    xb, w1t, w2t, tgt);
  k_gemm1<<<(B_ROWS/256) * (HID/256), 512, 0, stream>>>(xb, w1t, w2t, b1, pbuf);
  k_red  <<<B_ROWS / 128, 256, 0, stream>>>(pbuf, b2, tgt, loss);
}

// Round 7
// 269.027 us; speedup vs baseline: 1.9591x; 1.0023x over previous
//
#include <hip/hip_runtime.h>
#include <hip/hip_bf16.h>
#include <stdint.h>

// Problem constants
#define B_ROWS 32768
#define NUM_IN 1024
#define D_PAD2 1088   // 1064 padded to 17*64 K-tiles (8 dbuf iterations + 1 tail tile)
#define HID    2048
#define NPAD   64     // 37 logits padded to 64

typedef __attribute__((ext_vector_type(8))) short bf16x8;
typedef __attribute__((ext_vector_type(4))) float f32x4;
typedef unsigned short ushort_t;

__device__ __forceinline__ unsigned short f2bf(float f){
  union { float f; uint32_t u; } x; x.f = f;
  uint32_t u = x.u;
  return (unsigned short)((u + 0x7FFFu + ((u >> 16) & 1u)) >> 16);
}

__device__ __forceinline__ void gload16(const void* g, void* l){
  __builtin_amdgcn_global_load_lds((const __attribute__((address_space(1))) void*)g,
                                   (__attribute__((address_space(3))) void*)l, 16, 0, 0);
}

// ---------------- discretizer scan (per batch element) ----------------
__device__ __forceinline__ int disc_step(
    float cam0, float cam1, const int a[5],
    float& ac0, float& ac1, float& delta,
    int r[5], bool& dch, int& cam_steps, bool& committed, float& norm)
{
  const int RS[5] = {6, 8, 10, 11, 14};
  norm += committed ? 0.0f : 1.0f;
  bool commit = ((fabsf(cam0) < 1e-5f) && (fabsf(cam1) < 1e-5f)) || (cam_steps >= 6);
  #pragma unroll
  for (int i = 0; i < 5; ++i) commit = commit && (r[i] == a[i]);
  int dac = 0;
  bool modified = commit;
  #pragma unroll
  for (int i = 0; i < 5; ++i){
    bool disc = (!modified) && (r[i] != a[i]);
    if (disc){
      dac = (a[i] == 0) ? (r[i] - 1 + RS[i]) : (a[i] - 1 + RS[i]);
      r[i] = a[i];
      modified = true;
    }
  }
  float d2 = delta * 2.0f;
  // NOTE: reference compares BOTH cam0 and cam1 against ac[:,0] — replicate.
  bool dmask = (!modified) && (!dch) &&
               ((fabsf(cam0 - ac0) > d2) || (fabsf(cam1 - ac0) > d2));
  if (dmask){ dac = 5; delta = fminf(d2, 0.5f); modified = true; }
  if (!modified){
    float sx = (cam0 < ac0) ? -1.0f : 1.0f;
    float sy = (cam1 < ac1) ? -1.0f : 1.0f;
    dac = (sx < 0.0f) ? ((sy < 0.0f) ? 1 : 3) : ((sy < 0.0f) ? 2 : 4);
    ac0 += sx * delta; ac1 += sy * delta;
    delta *= 0.5f;
    dch = true;
    cam_steps += 1;
  }
  committed = committed || commit;
  return dac;
}

// ---------------- fused prep: fc convert | W1^T (LDS transpose) | W2^T | disc ----------------
// block ranges: [0,16384) fc ; [16384,16928) w1t-transpose (17x32 tiles of 64x64);
//               [16928,17440) w2t ; [17440,17568) disc
__global__ void k_prep(const float* __restrict__ fc, const float* __restrict__ W1,
                       const float* __restrict__ W2,
                       const float* __restrict__ camera, const float* __restrict__ rand_u,
                       const int* __restrict__ afb, const int* __restrict__ alr,
                       const int* __restrict__ ajp, const int* __restrict__ ass,
                       const int* __restrict__ aat,
                       unsigned short* __restrict__ xb, unsigned short* __restrict__ w1t,
                       unsigned short* __restrict__ w2t, int* __restrict__ tgt)
{
  __shared__ float lt[64][65];      // transpose tile (+1 pad, conflict-free)
  const int b = blockIdx.x;
  const int tid = threadIdx.x;
  if (b < 16384){
    int gid = b * 256 + tid;
    int row = gid >> 7;
    int c   = gid & 127;
    const float4* p = (const float4*)(fc + (size_t)row * NUM_IN + c * 8);
    float4 f0 = p[0], f1 = p[1];
    uint4 pk;
    pk.x = (uint32_t)f2bf(f0.x) | ((uint32_t)f2bf(f0.y) << 16);
    pk.y = (uint32_t)f2bf(f0.z) | ((uint32_t)f2bf(f0.w) << 16);
    pk.z = (uint32_t)f2bf(f1.x) | ((uint32_t)f2bf(f1.y) << 16);
    pk.w = (uint32_t)f2bf(f1.z) | ((uint32_t)f2bf(f1.w) << 16);
    *(uint4*)(xb + (size_t)row * D_PAD2 + c * 8) = pk;
    return;
  }
  if (b < 16928){
    // W1 [1064][2048] -> w1t [2048][1088] via 64x64 LDS tile; coalesced both sides
    const int bi = b - 16384;
    const int kt = bi % 17, nt = bi / 17;
    const int k0 = kt * 64, n0 = nt * 64;
    const int c = tid & 63, rq = tid >> 6;
    #pragma unroll
    for (int rr = 0; rr < 16; ++rr){
      const int r = rr * 4 + rq;
      const int k = k0 + r;
      lt[r][c] = (k < 1064) ? W1[(size_t)k * HID + n0 + c] : 0.0f;
    }
    __syncthreads();
    #pragma unroll
    for (int rr = 0; rr < 16; ++rr){
      const int r = rr * 4 + rq;
      w1t[(size_t)(n0 + r) * D_PAD2 + k0 + c] = f2bf(lt[c][r]);
    }
    return;
  }
  if (b < 17440){
    int idx = (b - 16928) * 256 + tid;
    int n = idx >> 11;
    int k = idx & (HID - 1);
    float v = (n < 37) ? W2[(size_t)k * 37 + n] : 0.0f;
    w2t[idx] = f2bf(v);
    return;
  }
  // discretizer
  int row = (b - 17440) * 256 + tid;
  float cam0 = camera[2*row], cam1 = camera[2*row + 1];
  int a[5] = { afb[row], alr[row], ajp[row], ass[row], aat[row] };

  float ac0 = 0.f, ac1 = 0.f, delta = 0.0625f, norm = 0.f;
  int r[5] = {0,0,0,0,0};
  bool dch = false, committed = false; int cam_steps = 0;
  for (int t = 0; t < 20; ++t)
    disc_step(cam0, cam1, a, ac0, ac1, delta, r, dch, cam_steps, committed, norm);

  int rs = (int)(rand_u[row] * norm);
  if (rs > 19) rs = 19;
  if (rs < 0) rs = 0;

  ac0 = 0.f; ac1 = 0.f; delta = 0.0625f; norm = 0.f;
  r[0]=r[1]=r[2]=r[3]=r[4]=0; dch = false; committed = false; cam_steps = 0;
  for (int t = 0; t < rs; ++t)
    disc_step(cam0, cam1, a, ac0, ac1, delta, r, dch, cam_steps, committed, norm);

  float vec[40];
  #pragma unroll
  for (int j = 0; j < 40; ++j) vec[j] = 0.0f;
  vec[0] = ac0; vec[1] = ac1;
  const int offs[5] = {2, 5, 8, 10, 14};
  #pragma unroll
  for (int i = 0; i < 5; ++i) vec[offs[i] + r[i]] = 1.0f;
  vec[38] = delta; vec[39] = dch ? 1.0f : 0.0f;

  int dac = disc_step(cam0, cam1, a, ac0, ac1, delta, r, dch, cam_steps, committed, norm);
  tgt[row] = dac;

  unsigned short* o = xb + (size_t)row * D_PAD2 + NUM_IN;
  #pragma unroll
  for (int j = 0; j < 40; ++j) o[j] = f2bf(vec[j]);
  #pragma unroll
  for (int j = 40; j < 64; ++j) o[j] = 0;
}

// ---------------- GEMM1: 256x256, balanced-read 8-phase + fused W2 ----------------
// LDS regions (ushort offsets) for staging dest:
#define LDS_A0 0
#define LDS_A1 16384
#define LDS_B0 32768
#define LDS_B1 49152

#define STAGE(G, REG, ROW0, KT, HALF) do { \
    const ushort_t* s0_ = (G) + (size_t)((ROW0) + (HALF)*128 + srow) * D_PAD2 + ((KT) << 6) + scol; \
    gload16(s0_, lds + (REG) + (HALF)*8192 + t*8); \
    gload16(s0_ + (size_t)64 * D_PAD2, lds + (REG) + (HALF)*8192 + 4096 + t*8); \
  } while(0)

// A fragment batch (8 x ds_read_b128), BUF = 0 (A0) / 1 (A1): base + const offsets
#define LDA_(BUF, MH) do { \
    _Pragma("unroll") for (int mi_ = 0; mi_ < 4; ++mi_) \
    _Pragma("unroll") for (int kk_ = 0; kk_ < 2; ++kk_) \
      aR[mi_][kk_] = *(const bf16x8*)(aBk[kk_] + (BUF)*32768 + ((MH)*64 + mi_*16)*128); \
  } while(0)

// B half-quadrant (4 x ds_read_b128) into bank BR; BUF = 0 (B0) / 1 (B1)
#define LDB_(BUF, NH, BR) do { \
    _Pragma("unroll") for (int ni_ = 0; ni_ < 2; ++ni_) \
    _Pragma("unroll") for (int kk_ = 0; kk_ < 2; ++kk_) \
      BR[ni_][kk_] = *(const bf16x8*)(bBk[kk_] + (BUF)*32768 + ((NH)*32 + ni_*16)*128); \
  } while(0)

#define MMA(MH, NH, BR) do { \
    __builtin_amdgcn_s_setprio(1); \
    _Pragma("unroll") for (int mi_ = 0; mi_ < 4; ++mi_) \
    _Pragma("unroll") for (int ni_ = 0; ni_ < 2; ++ni_) \
    _Pragma("unroll") for (int kk_ = 0; kk_ < 2; ++kk_) \
      acc[(MH)*4+mi_][(NH)*2+ni_] = __builtin_amdgcn_mfma_f32_16x16x32_bf16( \
          aR[mi_][kk_], BR[ni_][kk_], acc[(MH)*4+mi_][(NH)*2+ni_], 0, 0, 0); \
    __builtin_amdgcn_s_setprio(0); \
  } while(0)

#define BAR() __builtin_amdgcn_s_barrier()
#define LGKM0()    asm volatile("s_waitcnt lgkmcnt(0)" ::: "memory")
#define LGKM8()    asm volatile("s_waitcnt lgkmcnt(8)" ::: "memory")
#define WAIT_VM4() asm volatile("s_waitcnt vmcnt(4)" ::: "memory")
#define WAIT_VM0() asm volatile("s_waitcnt vmcnt(0)" ::: "memory")

__global__ __launch_bounds__(512, 2) void k_gemm1(const ushort_t* __restrict__ xb,
                                                  const ushort_t* __restrict__ w1t,
                                                  const ushort_t* __restrict__ w2t,
                                                  const float* __restrict__ b1,
                                                  float* __restrict__ pbuf)
{
  __shared__ ushort_t lds[65536];   // 128 KiB
  const int t = threadIdx.x;        // 0..511
  const int lane = t & 63;
  const int wid = t >> 6, wm = wid >> 2, wn = wid & 3;
  const int lr = lane & 15, lg = lane >> 4;

  // XCD-aware swizzle (nwg=1024 divisible by 8 -> bijective).
  const int bid = blockIdx.x;
  const int swz = (bid & 7) * 128 + (bid >> 3);
  const int brow = (swz >> 3) << 8;
  const int bcol = (swz & 7) << 8;

  // staging coords
  const int srow = t >> 3;
  const int scol = ((t & 7) ^ (srow & 7)) << 3;

  // fragment coords
  const int axor = lr & 7;
  const int arow_base = wm*128 + lr;
  const int brow_base = wn*64 + lr;

  // constant-offset read bases: kk-indexed chunk XOR folded into 4 base pointers.
  // All read offsets < 65536 -> single ds_read_b128 with offset: immediate.
  const char* aBk[2];
  const char* bBk[2];
  aBk[0] = (const char*)lds + arow_base*128 + (((0*4+lg)^axor) << 4);
  aBk[1] = (const char*)lds + arow_base*128 + (((1*4+lg)^axor) << 4);
  bBk[0] = (const char*)lds + 65536 + brow_base*128 + (((0*4+lg)^axor) << 4);
  bBk[1] = (const char*)lds + 65536 + brow_base*128 + (((1*4+lg)^axor) << 4);

  f32x4 acc[8][4] = {};
  bf16x8 aR[4][2], bR0[2][2], bR1[2][2];

  // ---- prologue: A0,B0 <- tile 0 ; B1 <- tile 1 (plays "prev P7/P8")
  STAGE(xb,  LDS_A0, brow, 0, 0);  STAGE(xb,  LDS_A0, brow, 0, 1);
  STAGE(w1t, LDS_B0, bcol, 0, 0);  STAGE(w1t, LDS_B0, bcol, 0, 1);
  STAGE(w1t, LDS_B1, bcol, 1, 0);  STAGE(w1t, LDS_B1, bcol, 1, 1);
  WAIT_VM4();            // leave B1's 4 instr outstanding -> tile0 A0/B0 landed
  BAR();

  // 8 iterations over tiles 0..15; tile 16 in tail.
  // Reads/phase: 12,4,8,0,12,4,8,0 (m201 distribution). Stages:
  // P1:A1h0(c1) P2:A1h1(c1) P3:B0h0(n0) P4:B0h1(n0) P5:A0h0(n0) P6:A0h1(n0)
  // P7:B1h0(n1) P8:B1h1(n1).  vmcnt(4) at P4 (drains prev-B1 + cur-A1) and
  // P8 (drains B0/A0 tile n0).
  for (int i = 0; i < 8; ++i){
    const int c1 = 2*i + 1;
    const int n0 = 2*i + 2;
    const int n1 = (2*i + 3 <= 16) ? 2*i + 3 : 16;   // i=7: garbage restage, benign

    // P1: reads A0mh0(8) + B0nh0(4) ; stage A1h0(c1)
    LDA_(0, 0); LDB_(0, 0, bR0);
    STAGE(xb, LDS_A1, brow, c1, 0);
    LGKM8();
    BAR(); LGKM0();
    MMA(0, 0, bR0);
    BAR();
    // P2: reads B0nh1(4) ; stage A1h1(c1)
    LDB_(0, 1, bR1);
    STAGE(xb, LDS_A1, brow, c1, 1);
    BAR(); LGKM0();
    MMA(0, 1, bR1);
    BAR();
    // P3: reads A0mh1(8) ; stage B0h0(n0)  (B0 reads drained at P2's LGKM0)
    LDA_(0, 1);
    STAGE(w1t, LDS_B0, bcol, n0, 0);
    BAR(); LGKM0();
    MMA(1, 0, bR0);
    BAR();
    // P4: stage B0h1(n0) ; vmcnt(4) -> A1(c1) + B1(c1, prev) landed
    STAGE(w1t, LDS_B0, bcol, n0, 1);
    WAIT_VM4();
    BAR();
    MMA(1, 1, bR1);
    BAR();
    // P5: reads A1mh0(8) + B1nh0(4) ; stage A0h0(n0)  (A0 reads drained at P3)
    LDA_(1, 0); LDB_(1, 0, bR0);
    STAGE(xb, LDS_A0, brow, n0, 0);
    LGKM8();
    BAR(); LGKM0();
    MMA(0, 0, bR0);
    BAR();
    // P6: reads B1nh1(4) ; stage A0h1(n0)
    LDB_(1, 1, bR1);
    STAGE(xb, LDS_A0, brow, n0, 1);
    BAR(); LGKM0();
    MMA(0, 1, bR1);
    BAR();
    // P7: reads A1mh1(8) ; stage B1h0(n1)  (B1 reads drained at P6)
    LDA_(1, 1);
    STAGE(w1t, LDS_B1, bcol, n1, 0);
    BAR(); LGKM0();
    MMA(1, 0, bR0);
    BAR();
    // P8: stage B1h1(n1) ; vmcnt(4) -> B0/A0 (tile n0) landed
    STAGE(w1t, LDS_B1, bcol, n1, 1);
    WAIT_VM4();
    BAR();
    MMA(1, 1, bR1);
    BAR();
  }

  // ---- tail: tile 16 in A0/B0 (landed per last P8's vmcnt(4)+BAR)
  LDA_(0, 0); LDB_(0, 0, bR0); LDB_(0, 1, bR1);
  LGKM0();
  MMA(0, 0, bR0); MMA(0, 1, bR1);
  LDA_(0, 1);
  LGKM0();
  MMA(1, 0, bR0); MMA(1, 1, bR1);

  // ---- fused epilogue ----
  bf16x8 w2fA[4][4];
  #pragma unroll
  for (int ks = 0; ks < 4; ++ks)
    #pragma unroll
    for (int ni = 0; ni < 4; ++ni)
      w2fA[ks][ni] = *(const bf16x8*)(w2t + (size_t)(ni*16 + lr) * HID + bcol + ks*32 + lg*8);

  // Drain pending (garbage) prefetches before reusing LDS, then sync.
  WAIT_VM0();
  BAR();

  float b1v[4];
  #pragma unroll
  for (int ni = 0; ni < 4; ++ni) b1v[ni] = b1[bcol + wn*64 + ni*16 + lr];

  // silu + pack to bf16; scatter into LDS as [row 256][col 256] with chunk-XOR swizzle
  #pragma unroll
  for (int mi = 0; mi < 8; ++mi){
    #pragma unroll
    for (int ni = 0; ni < 4; ++ni){
      const int col = wn*64 + ni*16 + lr;
      #pragma unroll
      for (int i2 = 0; i2 < 4; ++i2){
        const int row = wm*128 + mi*16 + lg*4 + i2;
        float v = acc[mi][ni][i2] + b1v[ni];
        float s = v / (1.0f + __expf(-v));     // silu
        const int chunk = (col >> 3) ^ (row & 7);
        lds[row*256 + chunk*8 + (col & 7)] = f2bf(s);
      }
    }
  }
  __syncthreads();

  bf16x8 w2fB[4][4];
  #pragma unroll
  for (int ks = 0; ks < 4; ++ks)
    #pragma unroll
    for (int ni = 0; ni < 4; ++ni)
      w2fB[ks][ni] = *(const bf16x8*)(w2t + (size_t)(ni*16 + lr) * HID + bcol + (ks+4)*32 + lg*8);

  // mini-GEMM: partial[r][n] = hTile[r][:256] @ W2chunk[:256][n], n in [0,64)
  const int rb = wid * 32;
  f32x4 acc2[2][4] = {};
  #pragma unroll
  for (int ks = 0; ks < 8; ++ks){
    bf16x8 a2[2];
    #pragma unroll
    for (int m = 0; m < 2; ++m){
      const int row = rb + m*16 + lr;
      a2[m] = *(const bf16x8*)(lds + row*256 + (((ks*4+lg) ^ (lr & 7)) << 3));
    }
    #pragma unroll
    for (int m = 0; m < 2; ++m)
      #pragma unroll
      for (int ni = 0; ni < 4; ++ni)
        acc2[m][ni] = __builtin_amdgcn_mfma_f32_16x16x32_bf16(
            a2[m], (ks < 4) ? w2fA[ks & 3][ni] : w2fB[ks & 3][ni], acc2[m][ni], 0, 0, 0);
  }

  // store partials: pbuf[cb][row][col]
  const int cb = bcol >> 8;
  #pragma unroll
  for (int m = 0; m < 2; ++m)
    #pragma unroll
    for (int ni = 0; ni < 4; ++ni)
      #pragma unroll
      for (int i2 = 0; i2 < 4; ++i2){
        const int r = brow + rb + m*16 + lg*4 + i2;
        pbuf[((size_t)cb << 21) + ((size_t)r << 6) + ni*16 + lr] = acc2[m][ni][i2];
      }
}

// ---------------- reduce: sum partials + b2 -> log-softmax -> NLL ----------------
__global__ __launch_bounds__(256) void k_red(const float* __restrict__ pbuf,
                                             const float* __restrict__ b2,
                                             const int* __restrict__ tgt,
                                             float* __restrict__ loss)
{
  const int lane = threadIdx.x & 63, w = threadIdx.x >> 6;
  const int row0 = blockIdx.x * 128 + w * 32;
  const float bias = (lane < 37) ? b2[lane] : 0.0f;
  for (int i = 0; i < 32; ++i){
    const int r = row0 + i;
    float s = 0.0f;
    #pragma unroll
    for (int cb = 0; cb < 8; ++cb)
      s += pbuf[((size_t)cb << 21) + ((size_t)r << 6) + lane];
    float x = (lane < 37) ? (s + bias) : -1e30f;
    float m = x;
    #pragma unroll
    for (int off = 1; off < 64; off <<= 1) m = fmaxf(m, __shfl_xor(m, off, 64));
    float e = __expf(x - m);
    float se = e;
    #pragma unroll
    for (int off = 1; off < 64; off <<= 1) se += __shfl_xor(se, off, 64);
    const int tg = tgt[r];
    const float pick = __shfl(x, tg, 64);
    if (lane == 0) loss[r] = m + __logf(se) - pick;
  }
}

// ---------------- launch ----------------
extern "C" void kernel_launch(void* const* d_in, const int* in_sizes, int n_in,
                              void* d_out, int out_size, void* d_ws, size_t ws_size,
                              hipStream_t stream)
{
  (void)in_sizes; (void)n_in; (void)out_size; (void)ws_size;
  const float* fc  = (const float*)d_in[0];
  const float* cam = (const float*)d_in[1];
  const float* ru  = (const float*)d_in[2];
  const float* W1  = (const float*)d_in[3];
  const float* b1  = (const float*)d_in[4];
  const float* W2  = (const float*)d_in[5];
  const float* b2  = (const float*)d_in[6];
  const int* afb = (const int*)d_in[7];
  const int* alr = (const int*)d_in[8];
  const int* ajp = (const int*)d_in[9];
  const int* ass = (const int*)d_in[10];
  const int* aat = (const int*)d_in[11];
  float* loss = (float*)d_out;

  // workspace layout (bytes):
  // xb   : 32768 x 1088 bf16  = 71,303,168
  // w1t  : 2048 x 1088 bf16   =  4,456,448
  // w2t  : 64 x 2048 bf16     =    262,144
  // tgt  : 32768 int32        =    131,072
  // pbuf : 8 x 32768 x 64 f32 = 67,108,864   (total ~136.6 MiB)
  char* ws = (char*)d_ws;
  unsigned short* xb  = (unsigned short*)(ws);
  unsigned short* w1t = (unsigned short*)(ws + 71303168);
  unsigned short* w2t = (unsigned short*)(ws + 75759616);
  int*            tgt = (int*)           (ws + 76021760);
  float*          pbuf= (float*)         (ws + 76152832);

  // fused prep: fc(16384) + w1t-transpose(544) + w2t(512) + disc(128) = 17568 blocks
  k_prep<<<17568, 256, 0, stream>>>(fc, W1, W2, cam, ru, afb, alr, ajp, ass, aat,
                                    xb, w1t, w2t, tgt);
  k_gemm1<<<(B_ROWS/256) * (HID/256), 512, 0, stream>>>(xb, w1t, w2t, b1, pbuf);
  k_red  <<<B_ROWS / 128, 256, 0, stream>>>(pbuf, b2, tgt, loss);
}